// Round 5
// baseline (807.093 us; speedup 1.0000x reference)
//
#include <hip/hip_runtime.h>
#include <hip/hip_bf16.h>
#include <math.h>

// ---------------- problem constants ----------------
#define OC     256
#define IC     128
#define HW     56
#define NB     64
#define KK     1152          // IC*9
#define HP     58            // padded spatial
#define PIX    (HW*HW)       // 3136
#define XPAD_ELEMS ((long)NB*HP*HP*IC)   // 27,557,888
#define A_ELEMS    (OC*KK)               // 294,912

typedef __attribute__((ext_vector_type(8))) short          bf16x8;
typedef __attribute__((ext_vector_type(8))) unsigned short u16x8;
typedef __attribute__((ext_vector_type(4))) float          f32x4;

__device__ __forceinline__ void async_load16(const void* g, void* l) {
    __builtin_amdgcn_global_load_lds(
        (const __attribute__((address_space(1))) void*)g,
        (__attribute__((address_space(3))) void*)l, 16, 0, 0);
}

// bf16 RNE convert
__device__ __forceinline__ unsigned short f2bf(float f) {
    unsigned int u = __float_as_uint(f);
    return (unsigned short)((u + 0x7fffu + ((u >> 16) & 1u)) >> 16);
}
__device__ __forceinline__ float bf2f(unsigned short b) {
    return __uint_as_float(((unsigned int)b) << 16);
}

// XOR-swizzled LDS element offset (2-way bank aliasing only — free, m136)
__device__ __forceinline__ int lds_off(int row, int q) {
    return row * 32 + (((q ^ (row >> 1)) & 3) << 3);
}

// ---------------- kernel 1: weights + BN constants ----------------
__global__ __launch_bounds__(256) void prep_weights(
        const float* __restrict__ phase, const float* __restrict__ gamma,
        const float* __restrict__ beta,  const float* __restrict__ rmean,
        const float* __restrict__ rvar,
        __hip_bfloat16* __restrict__ ah, __hip_bfloat16* __restrict__ al,
        float* __restrict__ scale, float* __restrict__ bias) {
    int g = blockIdx.x * 256 + threadIdx.x;      // 0 .. 294911
    int oc = g / KK;
    int kk = g - oc * KK;
    int kpos = kk >> 7;          // kh*3+kw
    int ic   = kk & 127;
    int j    = ic * 9 + kpos;    // original flat k = ic*9 + kh*3 + kw
    int pidx = (((oc >> 3) * 144 + (j >> 3)) * 8 + (oc & 7)) * 8 + (j & 7);
    double phi = (double)phase[pidx];
    double c   = cos(phi);
    const double a = 0.987, r = 0.99;
    double num = a*a - 2.0*a*r*c + r*r;
    double den = 1.0 - 2.0*a*r*c + (a*r)*(a*r);
    float t = (float)(num / den);
    unsigned short hb = f2bf(t);
    float hf = bf2f(hb);
    ((unsigned short*)ah)[g] = hb;
    ((unsigned short*)al)[g] = f2bf(t - hf);
    if (g < OC) {
        float inv = gamma[g] / sqrtf(rvar[g] + 1e-5f);
        scale[g] = inv;
        bias[g]  = beta[g] - rmean[g] * inv;
    }
}

// ---------------- kernel 2: pad + transpose + bf16 hi/lo split ----------------
__global__ __launch_bounds__(256) void prep_x(
        const float* __restrict__ x,
        __hip_bfloat16* __restrict__ xh, __hip_bfloat16* __restrict__ xl) {
    int hp  = blockIdx.x;    // 0..57
    int img = blockIdx.y;    // 0..63
    __shared__ float tile[IC * 57];   // [ic][w], stride 57
    int t = threadIdx.x;
    bool border = (hp == 0) || (hp == HP - 1);
    if (!border) {
        int h = hp - 1;
        const float* src = x + (long)img * IC * PIX + h * HW;
#pragma unroll
        for (int i = 0; i < 7; ++i) {            // 128*14 float4 = 1792
            int idx = i * 256 + t;
            int ic  = idx / 14;
            int w4  = (idx - ic * 14) * 4;
            float4 v = *(const float4*)&src[(long)ic * PIX + w4];
            tile[ic * 57 + w4 + 0] = v.x;
            tile[ic * 57 + w4 + 1] = v.y;
            tile[ic * 57 + w4 + 2] = v.z;
            tile[ic * 57 + w4 + 3] = v.w;
        }
    }
    __syncthreads();
    long base = ((long)(img * HP + hp)) * HP * IC;
#pragma unroll
    for (int i = 0; i < 4; ++i) {                // 58*16 = 928 vec-tasks
        int v = i * 256 + t;
        if (v < 928) {
            int icg = v & 15;                    // 8 ic per task
            int wp  = v >> 4;                    // 0..57
            bool inw = !border && wp >= 1 && wp <= HW;
            u16x8 hv, lv;
#pragma unroll
            for (int j = 0; j < 8; ++j) {
                float f = inw ? tile[(icg * 8 + j) * 57 + (wp - 1)] : 0.f;
                unsigned short hb = f2bf(f);
                hv[j] = hb;
                lv[j] = f2bf(f - bf2f(hb));
            }
            long o = base + wp * IC + icg * 8;
            *(u16x8*)&((unsigned short*)xh)[o] = hv;
            *(u16x8*)&((unsigned short*)xl)[o] = lv;
        }
    }
}

// ---------------- kernel 3: implicit GEMM conv + BN + ReLU6 ----------------
// R4: shrink the LDS term (diagnosis R0-R3: wall/chunk = MFMA 1862 + LDS 2048,
// pipes serialized; scheduler will not overlap them at this ratio).
//  - A (weights) bypasses LDS: per-wave global->VGPR fragment loads (L2-hot,
//    589 KB A-tile shared by 1600 blocks), one-chunk prefetch into a second
//    named register set, pinned by sched_barrier(0). Frag layout in regs
//    replicates the LDS-read mapping exactly: lane l holds row base+(l&15),
//    k-cols (l>>4)*8..+7 -> MFMA sequence and numerics bit-identical.
//  - B (x) stays DMA-staged, ring-3 of 16 KB slots (48 KB total), ONE barrier
//    per chunk. Slot read at body k is overwritten at body k+2 -> read-retire
//    hazard separated by a full body (~2k cyc) + consumption in body k+1.
//  - counted s_waitcnt vmcnt(12): drains B(k+1) DMAs [4] + A(k) loads [8];
//    B(k+2) [4] + A(k+1) [8] stay in flight across the barrier.
// New per-CU-chunk model: MFMA 1862, LDS 64 reads*12 + 32KB/128B = 1024.
__global__ __launch_bounds__(256, 2) void conv_gemm(
        const __hip_bfloat16* __restrict__ ah, const __hip_bfloat16* __restrict__ al,
        const __hip_bfloat16* __restrict__ xh, const __hip_bfloat16* __restrict__ xl,
        const float* __restrict__ scale, const float* __restrict__ bias,
        float* __restrict__ out) {
    __shared__ __hip_bfloat16 sBh[3][4096], sBl[3][4096];   // 48 KB

    // XCD-aware swizzle: consecutive blockIdx -> XCD round-robin (b&7).
    int b   = blockIdx.x;
    int xcd = b & 7;
    int idx = b >> 3;            // 0..399 per XCD
    int img = xcd * 8 + idx / 50;
    int rem = idx % 50;
    int mt  = rem >> 1;          // 0..24  pixel tile
    int ot  = rem & 1;           // oc tile

    int t    = threadIdx.x;
    int lane = t & 63;
    int wave = t >> 6;
    int wm   = wave & 1;     // oc half (64)
    int wn   = wave >> 1;    // pixel half (64)

    int row0 = t >> 2;
    int col0 = (((t & 3) ^ ((t >> 3) & 3))) << 3;

    // A: per-lane global base for register fragments (hi at pAg, lo at pAgl)
    const __hip_bfloat16* pAg  = ah + (long)(ot * 128 + wm * 64 + (lane & 15)) * KK
                                    + ((lane >> 4) << 3);
    const __hip_bfloat16* pAgl = al + (long)(ot * 128 + wm * 64 + (lane & 15)) * KK
                                    + ((lane >> 4) << 3);

    int m0 = mt * 128 + row0;      if (m0 > PIX - 1) m0 = PIX - 1;
    int m1 = mt * 128 + row0 + 64; if (m1 > PIX - 1) m1 = PIX - 1;
    int h0 = m0 / HW, w0 = m0 - h0 * HW;
    int h1 = m1 / HW, w1 = m1 - h1 * HW;
    const __hip_bfloat16* pxh0 = xh + (long)((img * HP + h0) * HP + w0) * IC + col0;
    const __hip_bfloat16* pxh1 = xh + (long)((img * HP + h1) * HP + w1) * IC + col0;
    const __hip_bfloat16* pxl0 = xl + (long)((img * HP + h0) * HP + w0) * IC + col0;
    const __hip_bfloat16* pxl1 = xl + (long)((img * HP + h1) * HP + w1) * IC + col0;

    int br[4];
#pragma unroll
    for (int f = 0; f < 4; ++f)
        br[f] = lds_off(wn * 64 + f * 16 + (lane & 15), lane >> 4);

    f32x4 acc[4][4];
#pragma unroll
    for (int i = 0; i < 4; ++i)
#pragma unroll
        for (int jj = 0; jj < 4; ++jj) acc[i][jj] = (f32x4){0.f, 0.f, 0.f, 0.f};

    bf16x8 aH0[4], aL0[4], bH0[4], bL0[4];   // even-chunk sets
    bf16x8 aH1[4], aL1[4], bH1[4], bL1[4];   // odd-chunk sets

// stage B of chunk ci into ring slot S (4 wave-DMAs, 16 KB/block)
#define ISSUE_B(ci, S)                                                         \
    {                                                                          \
        int bs = 32 * (ci) + ((ci) >= 12 ? 7040 : 0) + ((ci) >= 24 ? 7040 : 0);\
        async_load16(pxh0 + bs, &sBh[S][t * 8]);                               \
        async_load16(pxh1 + bs, &sBh[S][2048 + t * 8]);                        \
        async_load16(pxl0 + bs, &sBl[S][t * 8]);                               \
        async_load16(pxl1 + bs, &sBl[S][2048 + t * 8]);                        \
    }

// A fragments of chunk ci, global -> registers (8 dwordx4 loads)
#define GLOAD_A(ci, AH, AL)                                                    \
    {                                                                          \
        long _o = (long)(ci) * 32;                                             \
        _Pragma("unroll")                                                      \
        for (int f = 0; f < 4; ++f) {                                          \
            AH[f] = *(const bf16x8*)(pAg  + (long)f * 16 * KK + _o);           \
            AL[f] = *(const bf16x8*)(pAgl + (long)f * 16 * KK + _o);           \
        }                                                                      \
    }

#define READ_B(S, BH, BL)                                                      \
    {                                                                          \
        _Pragma("unroll")                                                      \
        for (int f = 0; f < 4; ++f) {                                          \
            BH[f] = *(const bf16x8*)&sBh[S][br[f]];                            \
            BL[f] = *(const bf16x8*)&sBl[S][br[f]];                            \
        }                                                                      \
    }

#define MFMAS(AH, AL, BH, BL)                                                  \
    {                                                                          \
        __builtin_amdgcn_s_setprio(1);                                         \
        _Pragma("unroll")                                                      \
        for (int fm = 0; fm < 4; ++fm)                                         \
            _Pragma("unroll")                                                  \
            for (int fn = 0; fn < 4; ++fn) {                                   \
                acc[fm][fn] = __builtin_amdgcn_mfma_f32_16x16x32_bf16(AL[fm], BH[fn], acc[fm][fn], 0, 0, 0); \
                acc[fm][fn] = __builtin_amdgcn_mfma_f32_16x16x32_bf16(AH[fm], BL[fn], acc[fm][fn], 0, 0, 0); \
                acc[fm][fn] = __builtin_amdgcn_mfma_f32_16x16x32_bf16(AH[fm], BH[fn], acc[fm][fn], 0, 0, 0); \
            }                                                                  \
        __builtin_amdgcn_s_setprio(0);                                         \
    }

// body k: stage B(k+2) -> slot (k+2)%3; prefetch A(k+1) -> next reg set;
// vmcnt(12) drains B(k+1)+A(k); barrier; read B(k+1) frags (overlaps MFMAS
// at the scheduler's discretion - no fence between them); MFMA chunk k.
#define BODY(k, VMC, AHc, ALc, BHc, BLc, AHn, ALn, BHn, BLn)                   \
    ISSUE_B((k) + 2, ((k) + 2) % 3);                                           \
    __builtin_amdgcn_sched_barrier(0);                                         \
    GLOAD_A((k) + 1, AHn, ALn);                                                \
    __builtin_amdgcn_sched_barrier(0);                                         \
    asm volatile("s_waitcnt vmcnt(" #VMC ")" ::: "memory");                    \
    __builtin_amdgcn_s_barrier();                                              \
    __builtin_amdgcn_sched_barrier(0);                                         \
    READ_B(((k) + 1) % 3, BHn, BLn);                                           \
    MFMAS(AHc, ALc, BHc, BLc);

    // prologue: stage B(0),B(1); load A(0); wait B(0); read B(0) frags
    ISSUE_B(0, 0);
    ISSUE_B(1, 1);
    __builtin_amdgcn_sched_barrier(0);
    GLOAD_A(0, aH0, aL0);
    __builtin_amdgcn_sched_barrier(0);
    asm volatile("s_waitcnt vmcnt(12)" ::: "memory");   // drain B(0); keep B(1)+A(0)
    __builtin_amdgcn_s_barrier();
    __builtin_amdgcn_sched_barrier(0);
    READ_B(0, bH0, bL0);

#pragma unroll 1
    for (int it = 0; it < 5; ++it) {         // bodies k = 6it .. 6it+5 (0..29)
        int k = it * 6;
        BODY(k + 0, 12, aH0, aL0, bH0, bL0, aH1, aL1, bH1, bL1)
        BODY(k + 1, 12, aH1, aL1, bH1, bL1, aH0, aL0, bH0, bL0)
        BODY(k + 2, 12, aH0, aL0, bH0, bL0, aH1, aL1, bH1, bL1)
        BODY(k + 3, 12, aH1, aL1, bH1, bL1, aH0, aL0, bH0, bL0)
        BODY(k + 4, 12, aH0, aL0, bH0, bL0, aH1, aL1, bH1, bL1)
        BODY(k + 5, 12, aH1, aL1, bH1, bL1, aH0, aL0, bH0, bL0)
    }
    // bodies 30..33 (stage B(32..35))
    BODY(30, 12, aH0, aL0, bH0, bL0, aH1, aL1, bH1, bL1)
    BODY(31, 12, aH1, aL1, bH1, bL1, aH0, aL0, bH0, bL0)
    BODY(32, 12, aH0, aL0, bH0, bL0, aH1, aL1, bH1, bL1)
    BODY(33, 12, aH1, aL1, bH1, bL1, aH0, aL0, bH0, bL0)
    // body 34: no staging; prefetch A(35); wait B(35)+A(34) (keep A(35)=8)
    GLOAD_A(35, aH1, aL1);
    __builtin_amdgcn_sched_barrier(0);
    asm volatile("s_waitcnt vmcnt(8)" ::: "memory");
    __builtin_amdgcn_s_barrier();
    __builtin_amdgcn_sched_barrier(0);
    READ_B(2, bH1, bL1);                     // B(35): slot 35%3 = 2
    MFMAS(aH0, aL0, bH0, bL0)                // chunk 34
    // body 35: compiler auto-waits A(35) regs; B(35) frags already read
    MFMAS(aH1, aL1, bH1, bL1)                // chunk 35

#undef ISSUE_B
#undef GLOAD_A
#undef READ_B
#undef MFMAS
#undef BODY

    // epilogue: BN (eval) + ReLU6, store fp32
    int pixc = mt * 128 + wn * 64 + (lane & 15);
    int occ0 = ot * 128 + wm * 64 + ((lane >> 4) << 2);
#pragma unroll
    for (int fm = 0; fm < 4; ++fm) {
#pragma unroll
        for (int r = 0; r < 4; ++r) {
            int oc = occ0 + fm * 16 + r;
            float sc = scale[oc], bi = bias[oc];
            long obase = ((long)(img * OC + oc)) * PIX;
#pragma unroll
            for (int fn = 0; fn < 4; ++fn) {
                int pix = pixc + fn * 16;
                if (pix < PIX) {
                    float v = acc[fm][fn][r] * sc + bi;
                    v = fminf(fmaxf(v, 0.f), 6.f);
                    out[obase + pix] = v;
                }
            }
        }
    }
}

// ---------------- launch ----------------
extern "C" void kernel_launch(void* const* d_in, const int* in_sizes, int n_in,
                              void* d_out, int out_size, void* d_ws, size_t ws_size,
                              hipStream_t stream) {
    const float* x     = (const float*)d_in[0];
    const float* phase = (const float*)d_in[1];
    const float* gamma = (const float*)d_in[2];
    const float* beta  = (const float*)d_in[3];
    const float* rmean = (const float*)d_in[4];
    const float* rvar  = (const float*)d_in[5];
    float* out = (float*)d_out;

    __hip_bfloat16* xh = (__hip_bfloat16*)d_ws;
    __hip_bfloat16* xl = xh + XPAD_ELEMS;
    __hip_bfloat16* ah = xl + XPAD_ELEMS;
    __hip_bfloat16* al = ah + A_ELEMS;
    float* scale = (float*)(al + A_ELEMS);
    float* bias  = scale + OC;

    prep_weights<<<A_ELEMS / 256, 256, 0, stream>>>(phase, gamma, beta, rmean, rvar,
                                                    ah, al, scale, bias);
    prep_x<<<dim3(HP, NB), 256, 0, stream>>>(x, xh, xl);
    conv_gemm<<<NB * 50, 256, 0, stream>>>(ah, al, xh, xl, scale, bias, out);
}

// Round 8
// 467.880 us; speedup vs baseline: 1.7250x; 1.7250x over previous
//
#include <hip/hip_runtime.h>
#include <math.h>

// ---------------- problem constants ----------------
#define OC     256
#define IC     128
#define HW     56
#define NB     64
#define KK     1152          // IC*9
#define HP     58            // padded spatial
#define PIX    (HW*HW)       // 3136
#define XQ_ELEMS ((long)NB*HP*HP*IC)     // 27,557,888 (i8 bytes)
#define A_ELEMS  (OC*KK)                 // 294,912

typedef __attribute__((ext_vector_type(4))) int  i32x4;
typedef __attribute__((ext_vector_type(8))) char c8x8;

// quantization scales: w in [0.0169, 0.99994] -> Sw; x clamped to +-6 -> Sx
#define SW 32512.0f
#define SX (32512.0f / 6.0f)

__device__ __forceinline__ void async_load16(const void* g, void* l) {
    __builtin_amdgcn_global_load_lds(
        (const __attribute__((address_space(1))) void*)g,
        (__attribute__((address_space(3))) void*)l, 16, 0, 0);
}

// LDS byte offset for i8 tiles: row stride 64 B (K=64), 4 slots of 16 B,
// XOR-swizzled by (row>>1)&3 -> 2 lanes/bank on frag reads (free, m136).
__device__ __forceinline__ int lds8(int row, int kg) {
    return row * 64 + (((kg ^ (row >> 1)) & 3) << 4);
}

// D = A*B + D, signed i8, K=64 (inline asm: ISA-verified opcode, avoids
// builtin-signature uncertainty; operand tie "+v" keeps C==D).
__device__ __forceinline__ void mfma8(i32x4& d, i32x4 a, i32x4 b) {
    asm("v_mfma_i32_16x16x64_i8 %0, %1, %2, %0" : "+v"(d) : "v"(a), "v"(b));
}

// ---------------- kernel 1: weights -> i8 hi/lo + BN constants ----------------
__global__ __launch_bounds__(256) void prep_weights(
        const float* __restrict__ phase, const float* __restrict__ gamma,
        const float* __restrict__ beta,  const float* __restrict__ rmean,
        const float* __restrict__ rvar,
        char* __restrict__ awh, char* __restrict__ awl,
        float* __restrict__ scale, float* __restrict__ bias) {
    int g = blockIdx.x * 256 + threadIdx.x;      // 0 .. 294911
    int oc = g / KK;
    int kk = g - oc * KK;
    int kpos = kk >> 7;          // kh*3+kw
    int ic   = kk & 127;
    int j    = ic * 9 + kpos;    // original flat k = ic*9 + kh*3 + kw
    int pidx = (((oc >> 3) * 144 + (j >> 3)) * 8 + (oc & 7)) * 8 + (j & 7);
    double phi = (double)phase[pidx];
    double c   = cos(phi);
    const double a = 0.987, r = 0.99;
    double num = a*a - 2.0*a*r*c + r*r;
    double den = 1.0 - 2.0*a*r*c + (a*r)*(a*r);
    float t = (float)(num / den);                // in [0.0169, 0.99994]
    int w16 = (int)(t * SW + 0.5f);              // [0, 32510]
    int wh  = (w16 + 128) >> 8;                  // [0, 127]
    awh[g] = (char)wh;
    awl[g] = (char)(w16 - (wh << 8));            // [-128, 127]
    if (g < OC) {
        float inv = gamma[g] / sqrtf(rvar[g] + 1e-5f);
        scale[g] = inv;
        bias[g]  = beta[g] - rmean[g] * inv;
    }
}

// ---------------- kernel 2: pad + transpose + i8 hi/lo quantize ----------------
__global__ __launch_bounds__(256) void prep_x(
        const float* __restrict__ x,
        char* __restrict__ xqh, char* __restrict__ xql) {
    int hp  = blockIdx.x;    // 0..57
    int img = blockIdx.y;    // 0..63
    __shared__ float tile[IC * 57];   // [ic][w], stride 57
    int t = threadIdx.x;
    bool border = (hp == 0) || (hp == HP - 1);
    if (!border) {
        int h = hp - 1;
        const float* src = x + (long)img * IC * PIX + h * HW;
#pragma unroll
        for (int i = 0; i < 7; ++i) {            // 128*14 float4 = 1792
            int idx = i * 256 + t;
            int ic  = idx / 14;
            int w4  = (idx - ic * 14) * 4;
            float4 v = *(const float4*)&src[(long)ic * PIX + w4];
            tile[ic * 57 + w4 + 0] = v.x;
            tile[ic * 57 + w4 + 1] = v.y;
            tile[ic * 57 + w4 + 2] = v.z;
            tile[ic * 57 + w4 + 3] = v.w;
        }
    }
    __syncthreads();
    long base = ((long)(img * HP + hp)) * HP * IC;
#pragma unroll
    for (int i = 0; i < 4; ++i) {                // 58*16 = 928 vec-tasks
        int v = i * 256 + t;
        if (v < 928) {
            int icg = v & 15;                    // 8 ic per task
            int wp  = v >> 4;                    // 0..57
            bool inw = !border && wp >= 1 && wp <= HW;
            c8x8 hv, lv;
#pragma unroll
            for (int j = 0; j < 8; ++j) {
                float f = inw ? tile[(icg * 8 + j) * 57 + (wp - 1)] : 0.f;
                float fc = fminf(6.f, fmaxf(-6.f, f));
                int xi = (int)rintf(fc * SX);    // [-32512, 32512]
                int xh = (xi + 128) >> 8;        // [-127, 127]
                hv[j] = (char)xh;
                lv[j] = (char)(xi - (xh << 8));  // [-128, 127]
            }
            long o = base + wp * IC + icg * 8;
            *(c8x8*)&xqh[o] = hv;
            *(c8x8*)&xql[o] = lv;
        }
    }
}

// ---------------- kernel 3: implicit GEMM conv (i8) + BN + ReLU6 ----------------
// R8: 16-bit fixed-point via i8 hi/lo pairs, 3x mfma_i32_16x16x64_i8 per frag:
//   hh -> acc_hh (weight 65536); hl+lh -> acc_mid (weight 256); ll dropped.
// i32 accumulation exact. Per-CU per K=64 chunk: MFMA 384x5.1=1959 cyc,
// LDS 128 reads x12 + 64KB/128B = 2048 cyc (both halved vs bf16-3-term).
// Structure: R2 skeleton, ring-2 32KB slots, single frag set (acc=128 VGPR),
// 2 barriers/chunk, counted vmcnt(8) (chunk k+2's 8 DMAs stay in flight).
__global__ __launch_bounds__(256, 2) void conv_gemm(
        const char* __restrict__ awh, const char* __restrict__ awl,
        const char* __restrict__ xqh, const char* __restrict__ xql,
        const float* __restrict__ scale, const float* __restrict__ bias,
        float* __restrict__ out) {
    __shared__ __align__(16) char sAh[2][8192], sAl[2][8192];
    __shared__ __align__(16) char sBh[2][8192], sBl[2][8192];   // 64 KB

    // XCD-aware swizzle: consecutive blockIdx -> XCD round-robin (b&7).
    int b   = blockIdx.x;
    int xcd = b & 7;
    int idx = b >> 3;            // 0..399 per XCD
    int img = xcd * 8 + idx / 50;
    int rem = idx % 50;
    int mt  = rem >> 1;          // 0..24  pixel tile
    int ot  = rem & 1;           // oc tile

    int t    = threadIdx.x;
    int lane = t & 63;
    int wave = t >> 6;
    int wm   = wave & 1;     // oc half (64)
    int wn   = wave >> 1;    // pixel half (64)

    int srow = t >> 2;                              // staging row in 64-half
    int scol = (((t & 3) ^ ((t >> 3) & 3))) << 4;   // pre-swizzled k-group (16 i8)

    const char* pw0 = awh + (long)(ot * 128 + srow) * KK + scol;
    const char* pw1 = pw0 + (long)64 * KK;
    const char* pl0 = awl + (long)(ot * 128 + srow) * KK + scol;
    const char* pl1 = pl0 + (long)64 * KK;

    int m0 = mt * 128 + srow;      if (m0 > PIX - 1) m0 = PIX - 1;
    int m1 = mt * 128 + srow + 64; if (m1 > PIX - 1) m1 = PIX - 1;
    int h0 = m0 / HW, w0 = m0 - h0 * HW;
    int h1 = m1 / HW, w1 = m1 - h1 * HW;
    const char* ph0 = xqh + (long)((img * HP + h0) * HP + w0) * IC + scol;
    const char* ph1 = xqh + (long)((img * HP + h1) * HP + w1) * IC + scol;
    const char* pq0 = xql + (long)((img * HP + h0) * HP + w0) * IC + scol;
    const char* pq1 = xql + (long)((img * HP + h1) * HP + w1) * IC + scol;

    int ar[4], br[4];
#pragma unroll
    for (int f = 0; f < 4; ++f) {
        ar[f] = lds8(wm * 64 + f * 16 + (lane & 15), lane >> 4);
        br[f] = lds8(wn * 64 + f * 16 + (lane & 15), lane >> 4);
    }

    i32x4 hh[4][4], mid[4][4];
#pragma unroll
    for (int i = 0; i < 4; ++i)
#pragma unroll
        for (int jj = 0; jj < 4; ++jj) {
            hh[i][jj]  = (i32x4){0, 0, 0, 0};
            mid[i][jj] = (i32x4){0, 0, 0, 0};
        }

    i32x4 aH[4], aL[4], bH[4], bL[4];   // single fragment set

// stage K=64 chunk ci into ring slot S: 8 wave-DMAs (A 16 KB + B 16 KB)
#define ISSUE(ci, S)                                                           \
    {                                                                          \
        long ko = (long)(ci) * 64;                                             \
        long bs = 64 * (ci) + ((ci) >= 6 ? 7040 : 0) + ((ci) >= 12 ? 7040 : 0);\
        async_load16(pw0 + ko, &sAh[S][t * 16]);                               \
        async_load16(pw1 + ko, &sAh[S][4096 + t * 16]);                        \
        async_load16(pl0 + ko, &sAl[S][t * 16]);                               \
        async_load16(pl1 + ko, &sAl[S][4096 + t * 16]);                        \
        async_load16(ph0 + bs, &sBh[S][t * 16]);                               \
        async_load16(ph1 + bs, &sBh[S][4096 + t * 16]);                        \
        async_load16(pq0 + bs, &sBl[S][t * 16]);                               \
        async_load16(pq1 + bs, &sBl[S][4096 + t * 16]);                        \
    }

#define READF(S)                                                               \
    {                                                                          \
        _Pragma("unroll")                                                      \
        for (int f = 0; f < 4; ++f) {                                          \
            aH[f] = *(const i32x4*)&sAh[S][ar[f]];                             \
            aL[f] = *(const i32x4*)&sAl[S][ar[f]];                             \
            bH[f] = *(const i32x4*)&sBh[S][br[f]];                             \
            bL[f] = *(const i32x4*)&sBl[S][br[f]];                             \
        }                                                                      \
    }

#define MFMAS()                                                                \
    {                                                                          \
        __builtin_amdgcn_s_setprio(1);                                         \
        _Pragma("unroll")                                                      \
        for (int fm = 0; fm < 4; ++fm)                                         \
            _Pragma("unroll")                                                  \
            for (int fn = 0; fn < 4; ++fn) {                                   \
                mfma8(hh[fm][fn],  aH[fm], bH[fn]);                            \
                mfma8(mid[fm][fn], aH[fm], bL[fn]);                            \
                mfma8(mid[fm][fn], aL[fm], bH[fn]);                            \
            }                                                                  \
        __builtin_amdgcn_s_setprio(0);                                         \
    }

// body k: chunk k is in slot k&1. Read frags(k); drain reads; barrier (all
// waves' reads done); overwrite slot with chunk k+2's DMAs; MFMA chunk k;
// vmcnt(8) = chunk k+1 landed (k+2's 8 stay in flight); barrier.
#define BODY(k)                                                                \
    READF((k) & 1);                                                            \
    asm volatile("s_waitcnt lgkmcnt(0)" ::: "memory");                         \
    __builtin_amdgcn_sched_barrier(0);                                         \
    __builtin_amdgcn_s_barrier();                                              \
    __builtin_amdgcn_sched_barrier(0);                                         \
    ISSUE((k) + 2, (k) & 1);                                                   \
    __builtin_amdgcn_sched_barrier(0);                                         \
    MFMAS();                                                                   \
    asm volatile("s_waitcnt vmcnt(8)" ::: "memory");                           \
    __builtin_amdgcn_s_barrier();                                              \
    __builtin_amdgcn_sched_barrier(0);

    // prologue: stage chunks 0,1; wait chunk 0 (chunk 1's 8 in flight)
    ISSUE(0, 0);
    ISSUE(1, 1);
    asm volatile("s_waitcnt vmcnt(8)" ::: "memory");
    __builtin_amdgcn_s_barrier();
    __builtin_amdgcn_sched_barrier(0);

#pragma unroll 1
    for (int k = 0; k < 16; ++k) {           // bodies 0..15 (stage 2..17)
        BODY(k)
    }
    // body 16: no staging left; drain chunk 17's DMAs after MFMA(16)
    READF(0);
    asm volatile("s_waitcnt lgkmcnt(0)" ::: "memory");
    __builtin_amdgcn_sched_barrier(0);
    __builtin_amdgcn_s_barrier();
    __builtin_amdgcn_sched_barrier(0);
    MFMAS();
    asm volatile("s_waitcnt vmcnt(0)" ::: "memory");
    __builtin_amdgcn_s_barrier();
    __builtin_amdgcn_sched_barrier(0);
    // body 17
    READF(1);
    asm volatile("s_waitcnt lgkmcnt(0)" ::: "memory");
    __builtin_amdgcn_sched_barrier(0);
    MFMAS();
#undef ISSUE
#undef READF
#undef MFMAS
#undef BODY

    asm volatile("s_nop 7\n\ts_nop 7");      // MFMA->VALU hazard insurance

    // epilogue: dequant + BN (eval) + ReLU6, store fp32
    const float invS = 1.0f / (SW * SX);
    int pixc = mt * 128 + wn * 64 + (lane & 15);
    int occ0 = ot * 128 + wm * 64 + ((lane >> 4) << 2);
#pragma unroll
    for (int fm = 0; fm < 4; ++fm) {
#pragma unroll
        for (int r = 0; r < 4; ++r) {
            int oc = occ0 + fm * 16 + r;
            float sc = scale[oc], bi = bias[oc];
            long obase = ((long)(img * OC + oc)) * PIX;
#pragma unroll
            for (int fn = 0; fn < 4; ++fn) {
                int pix = pixc + fn * 16;
                if (pix < PIX) {
                    float y = ((float)hh[fm][fn][r] * 65536.0f
                             + (float)mid[fm][fn][r] * 256.0f) * invS;
                    float v = y * sc + bi;
                    v = fminf(fmaxf(v, 0.f), 6.f);
                    out[obase + pix] = v;
                }
            }
        }
    }
}

// ---------------- launch ----------------
extern "C" void kernel_launch(void* const* d_in, const int* in_sizes, int n_in,
                              void* d_out, int out_size, void* d_ws, size_t ws_size,
                              hipStream_t stream) {
    const float* x     = (const float*)d_in[0];
    const float* phase = (const float*)d_in[1];
    const float* gamma = (const float*)d_in[2];
    const float* beta  = (const float*)d_in[3];
    const float* rmean = (const float*)d_in[4];
    const float* rvar  = (const float*)d_in[5];
    float* out = (float*)d_out;

    char* xqh = (char*)d_ws;
    char* xql = xqh + XQ_ELEMS;
    char* awh = xql + XQ_ELEMS;
    char* awl = awh + A_ELEMS;
    float* scale = (float*)(awl + A_ELEMS);
    float* bias  = scale + OC;

    prep_weights<<<A_ELEMS / 256, 256, 0, stream>>>(phase, gamma, beta, rmean, rvar,
                                                    awh, awl, scale, bias);
    prep_x<<<dim3(HP, NB), 256, 0, stream>>>(x, xqh, xql);
    conv_gemm<<<NB * 50, 256, 0, stream>>>(awh, awl, xqh, xql, scale, bias, out);
}